// Round 1
// baseline (729.826 us; speedup 1.0000x reference)
//
#include <hip/hip_runtime.h>
#include <hip/hip_bf16.h>

#define TD 4096
#define CD 512
#define CHD 64
#define NHEADS 8

typedef __attribute__((ext_vector_type(8))) short bf16x8;
typedef __attribute__((ext_vector_type(4))) short bf16x4;
typedef __attribute__((ext_vector_type(4))) float f32x4;

__device__ __forceinline__ short f2bf(float x){
  __hip_bfloat16 h = __float2bfloat16(x);
  return __builtin_bit_cast(short, h);
}
__device__ __forceinline__ float bf2f(short s){
  __hip_bfloat16 h = __builtin_bit_cast(__hip_bfloat16, s);
  return __bfloat162float(h);
}
#define MFMA16(a,b,c) __builtin_amdgcn_mfma_f32_16x16x32_bf16(a,b,c,0,0,0)

// ---------------- prep: split qkv_w into bf16 hi/lo, proj_w into bf16 ----------------
__global__ __launch_bounds__(256) void prep_w_kernel(
    const float* __restrict__ qkv_w, const float* __restrict__ proj_w,
    short* __restrict__ qw_hi, short* __restrict__ qw_lo, short* __restrict__ pw_bf)
{
  int i = blockIdx.x*256 + threadIdx.x;
  if(i < 1536*512){
    float v = qkv_w[i];
    short h = f2bf(v);
    qw_hi[i] = h;
    qw_lo[i] = f2bf(v - bf2f(h));
  }
  if(i < 512*512) pw_bf[i] = f2bf(proj_w[i]);
}

// ---------------- RMSNorm over C + transpose to (b, T, C), split hi/lo bf16 ----------------
__global__ __launch_bounds__(256) void rmsnorm_kernel(
    const float* __restrict__ x, const float* __restrict__ nw,
    short* __restrict__ xn_hi, short* __restrict__ xn_lo)
{
  const int b = blockIdx.y;
  const int t0 = blockIdx.x * 64;
  const int tid = threadIdx.x;
  const int tt = tid & 63, cg = tid >> 6;           // lane over t, 4 c-groups
  const float* xb = x + (size_t)b*CD*TD;

  float ss = 0.f;
  for(int c = cg; c < CD; c += 4){
    float v = xb[(size_t)c*TD + t0 + tt];
    ss += v*v;
  }
  __shared__ float red[4][64];
  __shared__ float fsc[64];
  red[cg][tt] = ss;
  __syncthreads();
  if(tid < 64){
    float s = red[0][tt]+red[1][tt]+red[2][tt]+red[3][tt];
    float mean = s * (1.0f/CD);
    fsc[tt] = sqrtf((float)CD / (mean + 1e-8f));    // sqrt(C)/rms
  }
  __syncthreads();

  __shared__ float tile[64][65];
  const int cl = tid & 63, tg = tid >> 6;
  for(int c0 = 0; c0 < CD; c0 += 64){
    for(int cc = cg; cc < 64; cc += 4)
      tile[cc][tt] = xb[(size_t)(c0+cc)*TD + t0 + tt];
    __syncthreads();
    float w = nw[c0 + cl];
    for(int tr = tg; tr < 64; tr += 4){
      float v = tile[cl][tr] * fsc[tr] * w;
      short h = f2bf(v);
      size_t o = ((size_t)b*TD + t0 + tr)*CD + c0 + cl;
      xn_hi[o] = h;
      xn_lo[o] = f2bf(v - bf2f(h));
    }
    __syncthreads();
  }
}

// ---------------- qkv GEMM: (1536x512)@(512xT) 3-pass hi/lo for q,k rows; 1-pass for v ----------------
// writes q,k scaled by ch^-0.25, split hi/lo bf16, layout (bh, 64, T); v bf16 (bh, 64, T)
__global__ __launch_bounds__(256) void qkv_gemm_kernel(
    const short* __restrict__ qw_hi, const short* __restrict__ qw_lo,
    const short* __restrict__ xn_hi, const short* __restrict__ xn_lo,
    const float* __restrict__ qkv_b,
    short* __restrict__ q_hi, short* __restrict__ q_lo,
    short* __restrict__ k_hi, short* __restrict__ k_lo,
    short* __restrict__ v_bf)
{
  __shared__ __align__(16) short Ah[64][72], Al[64][72], Bh[64][72], Bl[64][72];
  const int tid = threadIdx.x;
  const int m0 = blockIdx.x * 64;   // o-tile
  const int t0 = blockIdx.y * 64;   // t-tile
  const int b  = blockIdx.z;
  const bool three = (blockIdx.x % 3) != 2;   // q,k tiles need 3-pass; v tiles 1-pass
  const int w = tid >> 6, lane = tid & 63, ln = lane & 15, g = lane >> 4;
  const short* xh = xn_hi + (size_t)b*TD*CD;
  const short* xl = xn_lo + (size_t)b*TD*CD;

  f32x4 acc[4] = {};

  for(int k0 = 0; k0 < CD; k0 += 64){
    __syncthreads();
    for(int j = 0; j < 2; ++j){
      int chk = tid + 256*j;              // 512 chunks of 8 bf16
      int r = chk >> 3, c8 = (chk & 7)*8;
      *(bf16x8*)&Ah[r][c8] = *(const bf16x8*)&qw_hi[(size_t)(m0+r)*CD + k0 + c8];
      *(bf16x8*)&Bh[r][c8] = *(const bf16x8*)&xh[(size_t)(t0+r)*CD + k0 + c8];
      if(three){
        *(bf16x8*)&Al[r][c8] = *(const bf16x8*)&qw_lo[(size_t)(m0+r)*CD + k0 + c8];
        *(bf16x8*)&Bl[r][c8] = *(const bf16x8*)&xl[(size_t)(t0+r)*CD + k0 + c8];
      }
    }
    __syncthreads();
    #pragma unroll
    for(int ks = 0; ks < 2; ++ks){
      int ko = ks*32 + 8*g;
      bf16x8 ah = *(const bf16x8*)&Ah[w*16 + ln][ko];
      bf16x8 al = three ? *(const bf16x8*)&Al[w*16 + ln][ko] : ah;
      #pragma unroll
      for(int cf = 0; cf < 4; ++cf){
        bf16x8 bh = *(const bf16x8*)&Bh[cf*16 + ln][ko];
        acc[cf] = MFMA16(ah, bh, acc[cf]);
        if(three){
          bf16x8 bl = *(const bf16x8*)&Bl[cf*16 + ln][ko];
          acc[cf] = MFMA16(ah, bl, acc[cf]);
          acc[cf] = MFMA16(al, bh, acc[cf]);
        }
      }
    }
  }

  const float scale = 0.35355339059327373f;   // 64^-0.25
  #pragma unroll
  for(int cf = 0; cf < 4; ++cf){
    int t = t0 + cf*16 + ln;
    #pragma unroll
    for(int r = 0; r < 4; ++r){
      int o = m0 + w*16 + 4*g + r;
      int h = o / 192, rem = o % 192;
      int ty = rem >> 6, c = rem & 63;
      int bh_ = b*NHEADS + h;
      float v = acc[cf][r] + qkv_b[o];
      size_t idx = ((size_t)bh_*CHD + c)*TD + t;
      if(ty == 0){
        float vs = v * scale;
        short hh = f2bf(vs);
        q_hi[idx] = hh; q_lo[idx] = f2bf(vs - bf2f(hh));
      } else if(ty == 1){
        float vs = v * scale;
        short hh = f2bf(vs);
        k_hi[idx] = hh; k_lo[idx] = f2bf(vs - bf2f(hh));
      } else {
        v_bf[idx] = f2bf(v);
      }
    }
  }
}

// ---------------- flash attention: block = 64 q rows (4 waves x 16), iterate s in tiles of 64 ----------------
// S = 3-pass hi/lo bf16 MFMA (fp32-grade logits); online softmax fp32; PV 1-pass bf16.
// a written as (b, T, C) bf16 for the proj GEMM.
__global__ __launch_bounds__(256) void attn_kernel(
    const short* __restrict__ q_hi, const short* __restrict__ q_lo,
    const short* __restrict__ k_hi, const short* __restrict__ k_lo,
    const short* __restrict__ v_bf, short* __restrict__ a_t)
{
  __shared__ __align__(16) short Qh[64][72], Ql[64][72], Kh[64][72], Kl[64][72], Vt[64][72];
  __shared__ __align__(16) short Pl[4][16][72];
  const int tid = threadIdx.x;
  const int t0 = blockIdx.x * 64;
  const int bh = blockIdx.y;
  const int w = tid >> 6, lane = tid & 63, ln = lane & 15, g = lane >> 4;
  const short* qhg = q_hi + (size_t)bh*CHD*TD;
  const short* qlg = q_lo + (size_t)bh*CHD*TD;
  const short* khg = k_hi + (size_t)bh*CHD*TD;
  const short* klg = k_lo + (size_t)bh*CHD*TD;
  const short* vg  = v_bf + (size_t)bh*CHD*TD;

  // stage Q (transpose (c,t) -> LDS (t,c))
  for(int j = 0; j < 4; ++j){
    int chk = tid + 256*j;                 // 1024 chunks of 4 over t
    int c = chk >> 4, t4 = (chk & 15)*4;
    bf16x4 h4 = *(const bf16x4*)&qhg[(size_t)c*TD + t0 + t4];
    bf16x4 l4 = *(const bf16x4*)&qlg[(size_t)c*TD + t0 + t4];
    #pragma unroll
    for(int jj = 0; jj < 4; ++jj){ Qh[t4+jj][c] = h4[jj]; Ql[t4+jj][c] = l4[jj]; }
  }

  float m_run[4], l_run[4];
  f32x4 acco[4] = {};
  #pragma unroll
  for(int r = 0; r < 4; ++r){ m_run[r] = -1e30f; l_run[r] = 0.f; }

  for(int s0 = 0; s0 < TD; s0 += 64){
    __syncthreads();
    // stage K (transpose+keep hi/lo) and V (direct (c,s))
    for(int j = 0; j < 4; ++j){
      int chk = tid + 256*j;
      int c = chk >> 4, s4 = (chk & 15)*4;
      bf16x4 h4 = *(const bf16x4*)&khg[(size_t)c*TD + s0 + s4];
      bf16x4 l4 = *(const bf16x4*)&klg[(size_t)c*TD + s0 + s4];
      #pragma unroll
      for(int jj = 0; jj < 4; ++jj){ Kh[s4+jj][c] = h4[jj]; Kl[s4+jj][c] = l4[jj]; }
      *(bf16x4*)&Vt[c][s4] = *(const bf16x4*)&vg[(size_t)c*TD + s0 + s4];
    }
    __syncthreads();

    // S = Q^T K (3-pass)
    f32x4 s_acc[4] = {};
    #pragma unroll
    for(int ks = 0; ks < 2; ++ks){
      int ko = ks*32 + 8*g;
      bf16x8 qh8 = *(const bf16x8*)&Qh[w*16 + ln][ko];
      bf16x8 ql8 = *(const bf16x8*)&Ql[w*16 + ln][ko];
      #pragma unroll
      for(int sf = 0; sf < 4; ++sf){
        bf16x8 kh8 = *(const bf16x8*)&Kh[sf*16 + ln][ko];
        bf16x8 kl8 = *(const bf16x8*)&Kl[sf*16 + ln][ko];
        s_acc[sf] = MFMA16(qh8, kh8, s_acc[sf]);
        s_acc[sf] = MFMA16(qh8, kl8, s_acc[sf]);
        s_acc[sf] = MFMA16(ql8, kh8, s_acc[sf]);
      }
    }

    // online softmax per row (row t = w*16 + 4g + r; s spread across 16-lane group x 4 frags)
    float corr[4];
    #pragma unroll
    for(int r = 0; r < 4; ++r){
      float mt = fmaxf(fmaxf(s_acc[0][r], s_acc[1][r]), fmaxf(s_acc[2][r], s_acc[3][r]));
      #pragma unroll
      for(int m = 1; m < 16; m <<= 1) mt = fmaxf(mt, __shfl_xor(mt, m, 64));
      float mn = fmaxf(m_run[r], mt);
      corr[r] = __expf(m_run[r] - mn);
      m_run[r] = mn;
      float ls = 0.f;
      #pragma unroll
      for(int sf = 0; sf < 4; ++sf){
        float p = __expf(s_acc[sf][r] - mn);
        s_acc[sf][r] = p;
        ls += p;
      }
      #pragma unroll
      for(int m = 1; m < 16; m <<= 1) ls += __shfl_xor(ls, m, 64);
      l_run[r] = l_run[r]*corr[r] + ls;
    }

    // P -> per-wave LDS (bf16)
    #pragma unroll
    for(int sf = 0; sf < 4; ++sf)
      #pragma unroll
      for(int r = 0; r < 4; ++r)
        Pl[w][4*g + r][sf*16 + ln] = f2bf(s_acc[sf][r]);
    __syncthreads();

    // rescale accumulator, then acco += P V^T
    #pragma unroll
    for(int cf = 0; cf < 4; ++cf)
      #pragma unroll
      for(int r = 0; r < 4; ++r)
        acco[cf][r] *= corr[r];
    #pragma unroll
    for(int ks = 0; ks < 2; ++ks){
      int ko = ks*32 + 8*g;
      bf16x8 pa = *(const bf16x8*)&Pl[w][ln][ko];
      #pragma unroll
      for(int cf = 0; cf < 4; ++cf){
        bf16x8 vv = *(const bf16x8*)&Vt[cf*16 + ln][ko];
        acco[cf] = MFMA16(pa, vv, acco[cf]);
      }
    }
  }

  // epilogue: a_t[b][t][h*64 + c] = acco / l
  const int b = bh >> 3, h = bh & 7;
  #pragma unroll
  for(int r = 0; r < 4; ++r){
    float inv = 1.0f / l_run[r];
    int t = t0 + w*16 + 4*g + r;
    #pragma unroll
    for(int cf = 0; cf < 4; ++cf){
      int c = h*CHD + cf*16 + ln;
      a_t[((size_t)b*TD + t)*CD + c] = f2bf(acco[cf][r]*inv);
    }
  }
}

// ---------------- proj GEMM + bias + residual ----------------
__global__ __launch_bounds__(256) void proj_kernel(
    const short* __restrict__ pw_bf, const short* __restrict__ a_t,
    const float* __restrict__ proj_b, const float* __restrict__ x,
    float* __restrict__ out)
{
  __shared__ __align__(16) short As[64][72], Bs[64][72];
  const int tid = threadIdx.x;
  const int m0 = blockIdx.x * 64;
  const int t0 = blockIdx.y * 64;
  const int b  = blockIdx.z;
  const int w = tid >> 6, lane = tid & 63, ln = lane & 15, g = lane >> 4;
  const short* ab = a_t + (size_t)b*TD*CD;

  f32x4 acc[4] = {};
  for(int k0 = 0; k0 < CD; k0 += 64){
    __syncthreads();
    for(int j = 0; j < 2; ++j){
      int chk = tid + 256*j;
      int r = chk >> 3, c8 = (chk & 7)*8;
      *(bf16x8*)&As[r][c8] = *(const bf16x8*)&pw_bf[(size_t)(m0+r)*CD + k0 + c8];
      *(bf16x8*)&Bs[r][c8] = *(const bf16x8*)&ab[(size_t)(t0+r)*CD + k0 + c8];
    }
    __syncthreads();
    #pragma unroll
    for(int ks = 0; ks < 2; ++ks){
      int ko = ks*32 + 8*g;
      bf16x8 a8 = *(const bf16x8*)&As[w*16 + ln][ko];
      #pragma unroll
      for(int cf = 0; cf < 4; ++cf){
        bf16x8 b8 = *(const bf16x8*)&Bs[cf*16 + ln][ko];
        acc[cf] = MFMA16(a8, b8, acc[cf]);
      }
    }
  }
  #pragma unroll
  for(int cf = 0; cf < 4; ++cf){
    int t = t0 + cf*16 + ln;
    #pragma unroll
    for(int r = 0; r < 4; ++r){
      int o = m0 + w*16 + 4*g + r;
      size_t idx = ((size_t)(b*CD + o))*TD + t;
      out[idx] = acc[cf][r] + proj_b[o] + x[idx];
    }
  }
}

extern "C" void kernel_launch(void* const* d_in, const int* in_sizes, int n_in,
                              void* d_out, int out_size, void* d_ws, size_t ws_size,
                              hipStream_t stream)
{
  const float* x      = (const float*)d_in[0];
  const float* nw     = (const float*)d_in[1];
  const float* qkv_w  = (const float*)d_in[2];
  const float* qkv_b  = (const float*)d_in[3];
  const float* proj_w = (const float*)d_in[4];
  const float* proj_b = (const float*)d_in[5];
  float* out = (float*)d_out;

  char* ws = (char*)d_ws;
  size_t off = 0;
  auto alloc = [&](size_t bytes) -> void* {
    void* p = ws + off;
    off += (bytes + 255) & ~(size_t)255;
    return p;
  };
  short* xn_hi = (short*)alloc(2ull*TD*CD*2);
  short* xn_lo = (short*)alloc(2ull*TD*CD*2);
  short* qw_hi = (short*)alloc(1536ull*CD*2);
  short* qw_lo = (short*)alloc(1536ull*CD*2);
  short* pw_bf = (short*)alloc((size_t)CD*CD*2);
  short* q_hi  = (short*)alloc(16ull*CHD*TD*2);
  short* q_lo  = (short*)alloc(16ull*CHD*TD*2);
  short* k_hi  = (short*)alloc(16ull*CHD*TD*2);
  short* k_lo  = (short*)alloc(16ull*CHD*TD*2);
  short* v_bf  = (short*)alloc(16ull*CHD*TD*2);
  short* a_t   = (short*)alloc(2ull*TD*CD*2);

  prep_w_kernel<<<dim3(3072), dim3(256), 0, stream>>>(qkv_w, proj_w, qw_hi, qw_lo, pw_bf);
  rmsnorm_kernel<<<dim3(TD/64, 2), dim3(256), 0, stream>>>(x, nw, xn_hi, xn_lo);
  qkv_gemm_kernel<<<dim3(24, TD/64, 2), dim3(256), 0, stream>>>(qw_hi, qw_lo, xn_hi, xn_lo, qkv_b,
                                                                q_hi, q_lo, k_hi, k_lo, v_bf);
  attn_kernel<<<dim3(TD/64, 16), dim3(256), 0, stream>>>(q_hi, q_lo, k_hi, k_lo, v_bf, a_t);
  proj_kernel<<<dim3(CD/64, TD/64, 2), dim3(256), 0, stream>>>(pw_bf, a_t, proj_b, x, out);
}